// Round 1
// baseline (8706.833 us; speedup 1.0000x reference)
//
#include <hip/hip_runtime.h>
#include <cstdint>

#define HH 128
#define GG 384   // 3H
#define TT 4000
#define BB 64

__device__ __forceinline__ float sigmf(float x) {
  return 1.0f / (1.0f + __expf(-x));
}
__device__ __forceinline__ float tanh_fast(float x) {
  // tanh(x) = 2/(1+exp(-2x)) - 1 ; saturates correctly at +/-1 via inf/rcp
  return 2.0f / (1.0f + __expf(-2.0f * x)) - 1.0f;
}

template <int CTRL>
__device__ __forceinline__ float quad_add(float x) {
  int y = __builtin_amdgcn_mov_dpp(__float_as_int(x), CTRL, 0xF, 0xF, true);
  return x + __int_as_float(y);
}

// ---------------------------------------------------------------------------
// GRU recurrence: one block per batch element. 256 threads = 64 quads x 4
// k-chunks. Thread (q,c) owns 6 rows of Whh (r,z,n for j0=q and j1=q+64),
// k-range [32c, 32c+32), kept in 192 VGPRs. h lives in double-buffered LDS
// (padded layout: h[j] at (j>>5)*36 + (j&31) to spread chunk bases across
// banks). One __syncthreads per step.
// ---------------------------------------------------------------------------
__global__ __launch_bounds__(256, 1) void gru_rec(
    const float* __restrict__ gx,   // [B, T, 384] input contributions (bih included)
    const float* __restrict__ Whh,  // [384, 128]
    const float* __restrict__ bhh,  // [384]
    float* __restrict__ hout,       // [B, T, ldh]
    int ldh)
{
  __shared__ float hbuf[2][144];

  const int tid = threadIdx.x;
  const int q = tid >> 2;   // 0..63
  const int c = tid & 3;    // k-chunk
  const int b = blockIdx.x;

  const int j0 = q, j1 = q + 64;
  const int rows[6] = { j0, j0 + 128, j0 + 256, j1, j1 + 128, j1 + 256 };

  // --- load this thread's Whh rows (k-chunk) into registers ---
  float w[6][32];
  #pragma unroll
  for (int rr = 0; rr < 6; ++rr) {
    const float4* wp = reinterpret_cast<const float4*>(Whh + (size_t)rows[rr] * HH + c * 32);
    #pragma unroll
    for (int kq = 0; kq < 8; ++kq) {
      float4 v = wp[kq];
      w[rr][kq * 4 + 0] = v.x; w[rr][kq * 4 + 1] = v.y;
      w[rr][kq * 4 + 2] = v.z; w[rr][kq * 4 + 3] = v.w;
    }
  }
  float bh[6];
  #pragma unroll
  for (int rr = 0; rr < 6; ++rr) bh[rr] = bhh[rows[rr]];

  // zero h double-buffer
  for (int i = tid; i < 2 * 144; i += 256) (&hbuf[0][0])[i] = 0.0f;

  const float* gxb = gx + (size_t)b * TT * GG;
  float* houtb = hout + (size_t)b * TT * ldh;

  const int hoff0 = ((j0 >> 5) * 36) + (j0 & 31);
  const int hoff1 = ((j1 >> 5) * 36) + (j1 & 31);

  // preload gx(t=0)
  float gxc[6], gxn[6];
  #pragma unroll
  for (int rr = 0; rr < 6; ++rr) gxc[rr] = gxb[rows[rr]];

  __syncthreads();

  for (int t = 0; t < TT; ++t) {
    const int cur = t & 1, nxt = cur ^ 1;

    // prefetch next step's gx (clamped on last step; values unused)
    {
      const float* gxt = gxb + (size_t)(t + 1 < TT ? t + 1 : t) * GG;
      #pragma unroll
      for (int rr = 0; rr < 6; ++rr) gxn[rr] = gxt[rows[rr]];
    }

    // read my h chunk (32 values) from LDS
    float hv[32];
    {
      const float4* hp = reinterpret_cast<const float4*>(&hbuf[cur][c * 36]);
      #pragma unroll
      for (int kq = 0; kq < 8; ++kq) {
        float4 v = hp[kq];
        hv[kq * 4 + 0] = v.x; hv[kq * 4 + 1] = v.y;
        hv[kq * 4 + 2] = v.z; hv[kq * 4 + 3] = v.w;
      }
    }
    const float hold0 = hbuf[cur][hoff0];
    const float hold1 = hbuf[cur][hoff1];

    // 6 partial dot products over this chunk
    float a0 = 0.f, a1 = 0.f, a2 = 0.f, a3 = 0.f, a4 = 0.f, a5 = 0.f;
    #pragma unroll
    for (int kk = 0; kk < 32; ++kk) {
      const float h = hv[kk];
      a0 = fmaf(w[0][kk], h, a0);
      a1 = fmaf(w[1][kk], h, a1);
      a2 = fmaf(w[2][kk], h, a2);
      a3 = fmaf(w[3][kk], h, a3);
      a4 = fmaf(w[4][kk], h, a4);
      a5 = fmaf(w[5][kk], h, a5);
    }

    // butterfly across the 4 chunk lanes (quad_perm DPP: xor1 then xor2)
    a0 = quad_add<0xB1>(a0); a0 = quad_add<0x4E>(a0);
    a1 = quad_add<0xB1>(a1); a1 = quad_add<0x4E>(a1);
    a2 = quad_add<0xB1>(a2); a2 = quad_add<0x4E>(a2);
    a3 = quad_add<0xB1>(a3); a3 = quad_add<0x4E>(a3);
    a4 = quad_add<0xB1>(a4); a4 = quad_add<0x4E>(a4);
    a5 = quad_add<0xB1>(a5); a5 = quad_add<0x4E>(a5);

    // gates (PyTorch GRU): r,z,n; bhh_n inside r*(.)
    const float r0 = sigmf(gxc[0] + a0 + bh[0]);
    const float z0 = sigmf(gxc[1] + a1 + bh[1]);
    const float n0 = tanh_fast(gxc[2] + r0 * (a2 + bh[2]));
    const float h0 = (1.0f - z0) * n0 + z0 * hold0;

    const float r1 = sigmf(gxc[3] + a3 + bh[3]);
    const float z1 = sigmf(gxc[4] + a4 + bh[4]);
    const float n1 = tanh_fast(gxc[5] + r1 * (a5 + bh[5]));
    const float h1v = (1.0f - z1) * n1 + z1 * hold1;

    if (c == 0) {
      float* ho = houtb + (size_t)t * ldh;
      ho[j0] = h0;
      ho[j1] = h1v;
      hbuf[nxt][hoff0] = h0;
      hbuf[nxt][hoff1] = h1v;
    }

    #pragma unroll
    for (int rr = 0; rr < 6; ++rr) gxc[rr] = gxn[rr];

    __syncthreads();
  }
}

// ---------------------------------------------------------------------------
// Generic tiled GEMM: C[M,N] = A[M,K] * Bw[N,K]^T + bias (optional ReLU).
// 64x64 tile, K staged in 64-chunks (zero-padded), 256 threads, 4x4 per thread.
// ---------------------------------------------------------------------------
template <bool RELU>
__global__ __launch_bounds__(256) void gemm_bias(
    const float* __restrict__ A, int lda,
    const float* __restrict__ Bw,       // [N, K] row-major
    const float* __restrict__ bias,     // [N]
    float* __restrict__ C, int ldc,
    int M, int N, int K)
{
  __shared__ float As[64][65];
  __shared__ float Bs[64][65];

  const int tid = threadIdx.x;
  const int tx = tid & 15, ty = tid >> 4;
  const int row0 = blockIdx.x * 64, col0 = blockIdx.y * 64;

  float acc[4][4] = {};

  for (int k0 = 0; k0 < K; k0 += 64) {
    const int kc = (K - k0 < 64) ? (K - k0) : 64;

    #pragma unroll
    for (int l = 0; l < 16; ++l) {
      const int idx = tid + l * 256;
      const int r = idx >> 6, cc = idx & 63;
      As[r][cc] = (cc < kc) ? A[(size_t)(row0 + r) * lda + k0 + cc] : 0.0f;
      const int n = col0 + r;
      Bs[r][cc] = (cc < kc && n < N) ? Bw[(size_t)n * K + k0 + cc] : 0.0f;
    }
    __syncthreads();

    #pragma unroll 8
    for (int kk = 0; kk < 64; ++kk) {
      float av[4], bv[4];
      #pragma unroll
      for (int i = 0; i < 4; ++i) av[i] = As[ty * 4 + i][kk];
      #pragma unroll
      for (int j = 0; j < 4; ++j) bv[j] = Bs[tx * 4 + j][kk];
      #pragma unroll
      for (int i = 0; i < 4; ++i)
        #pragma unroll
        for (int j = 0; j < 4; ++j)
          acc[i][j] = fmaf(av[i], bv[j], acc[i][j]);
    }
    __syncthreads();
  }

  #pragma unroll
  for (int i = 0; i < 4; ++i) {
    const int r = row0 + ty * 4 + i;
    #pragma unroll
    for (int j = 0; j < 4; ++j) {
      const int cn = col0 + tx * 4 + j;
      if (cn < N) {
        float v = acc[i][j] + bias[cn];
        if (RELU) v = (v > 0.0f) ? v : 0.0f;
        C[(size_t)r * ldc + cn] = v;
      }
    }
  }
}

// ---------------------------------------------------------------------------
extern "C" void kernel_launch(void* const* d_in, const int* in_sizes, int n_in,
                              void* d_out, int out_size, void* d_ws, size_t ws_size,
                              hipStream_t stream) {
  const float* x    = (const float*)d_in[0];
  const float* Wih0 = (const float*)d_in[1];
  const float* Whh0 = (const float*)d_in[2];
  const float* bih0 = (const float*)d_in[3];
  const float* bhh0 = (const float*)d_in[4];
  const float* Wih1 = (const float*)d_in[5];
  const float* Whh1 = (const float*)d_in[6];
  const float* bih1 = (const float*)d_in[7];
  const float* bhh1 = (const float*)d_in[8];
  const float* W1   = (const float*)d_in[9];
  const float* b1   = (const float*)d_in[10];
  const float* W2   = (const float*)d_in[11];
  const float* b2   = (const float*)d_in[12];
  float* out = (float*)d_out;

  const int M = BB * TT;  // 256000 rows
  float* gxbuf = (float*)d_ws;                       // M*384 floats (393 MB)
  float* h1buf = gxbuf + (size_t)M * GG;             // M*128 floats (131 MB)

  dim3 blk(256);

  // 1) gx0 = x @ Wih0^T + bih0     [M,26]x[384,26]^T -> [M,384]
  gemm_bias<false><<<dim3(M / 64, 6), blk, 0, stream>>>(
      x, 26, Wih0, bih0, gxbuf, GG, M, GG, 26);

  // 2) layer-0 recurrence -> h1buf [B,T,128]
  gru_rec<<<dim3(BB), blk, 0, stream>>>(gxbuf, Whh0, bhh0, h1buf, HH);

  // 3) gx1 = h1 @ Wih1^T + bih1    [M,128]x[384,128]^T -> [M,384] (reuse gxbuf)
  gemm_bias<false><<<dim3(M / 64, 6), blk, 0, stream>>>(
      h1buf, HH, Wih1, bih1, gxbuf, GG, M, GG, HH);

  // 4) layer-1 recurrence -> h2 stored in-place in d_out rows (stride 136)
  gru_rec<<<dim3(BB), blk, 0, stream>>>(gxbuf, Whh1, bhh1, out, 136);

  // 5) hidden = relu(h2 @ W1^T + b1) -> h1buf   (reads d_out stride 136)
  gemm_bias<true><<<dim3(M / 64, 2), blk, 0, stream>>>(
      out, 136, W1, b1, h1buf, HH, M, HH, HH);

  // 6) out = hidden @ W2^T + b2 -> d_out (stride 136, N=136)
  gemm_bias<false><<<dim3(M / 64, 3), blk, 0, stream>>>(
      h1buf, HH, W2, b2, out, 136, M, 136, HH);
}

// Round 2
// 8301.301 us; speedup vs baseline: 1.0489x; 1.0489x over previous
//
#include <hip/hip_runtime.h>
#include <cstdint>

#define HH 128
#define GG 384   // 3H
#define TT 4000
#define BB 64

__device__ __forceinline__ float sigmf(float x) {
  return 1.0f / (1.0f + __expf(-x));
}
__device__ __forceinline__ float tanh_fast(float x) {
  return 2.0f / (1.0f + __expf(-2.0f * x)) - 1.0f;
}

template <int CTRL>
__device__ __forceinline__ float quad_add(float x) {
  int y = __builtin_amdgcn_mov_dpp(__float_as_int(x), CTRL, 0xF, 0xF, true);
  return x + __int_as_float(y);
}

// LDS-only barrier: do NOT drain vmcnt (keeps global prefetch in flight).
__device__ __forceinline__ void wg_barrier_lds() {
  asm volatile("s_waitcnt lgkmcnt(0)" ::: "memory");
  __builtin_amdgcn_s_barrier();
  asm volatile("" ::: "memory");
}

// ---------------------------------------------------------------------------
// GRU recurrence: one block per batch element, 256 threads = 64 quads x 4
// k-chunks. Thread (q,c) owns 6 rows of Whh in registers. h double-buffered
// in LDS. gx register-prefetched 4 steps ahead; per-step barrier is raw
// s_barrier + lgkmcnt(0) only, so gx loads are never drained by the barrier.
// ---------------------------------------------------------------------------
__global__ __launch_bounds__(256, 1) void gru_rec(
    const float* __restrict__ gx,   // [B, T, 384] input contributions (bih included)
    const float* __restrict__ Whh,  // [384, 128]
    const float* __restrict__ bhh,  // [384]
    float* __restrict__ hout,       // [B, T, ldh]
    int ldh)
{
  __shared__ float hbuf[2][144];

  const int tid = threadIdx.x;
  const int q = tid >> 2;   // 0..63
  const int c = tid & 3;    // k-chunk
  const int b = blockIdx.x;

  const int j0 = q, j1 = q + 64;
  const int rows[6] = { j0, j0 + 128, j0 + 256, j1, j1 + 128, j1 + 256 };

  // Whh rows (this thread's k-chunk) -> registers
  float w[6][32];
  #pragma unroll
  for (int rr = 0; rr < 6; ++rr) {
    const float4* wp = reinterpret_cast<const float4*>(Whh + (size_t)rows[rr] * HH + c * 32);
    #pragma unroll
    for (int kq = 0; kq < 8; ++kq) {
      float4 v = wp[kq];
      w[rr][kq * 4 + 0] = v.x; w[rr][kq * 4 + 1] = v.y;
      w[rr][kq * 4 + 2] = v.z; w[rr][kq * 4 + 3] = v.w;
    }
  }
  float bh[6];
  #pragma unroll
  for (int rr = 0; rr < 6; ++rr) bh[rr] = bhh[rows[rr]];

  for (int i = tid; i < 2 * 144; i += 256) (&hbuf[0][0])[i] = 0.0f;

  const float* gxb = gx + (size_t)b * TT * GG;
  float* houtb = hout + (size_t)b * TT * ldh;

  const int hoff0 = ((j0 >> 5) * 36) + (j0 & 31);
  const int hoff1 = ((j1 >> 5) * 36) + (j1 & 31);

  // prefetch gx for t = 0..3 (depth-4 rotating register buffer)
  float gxr[4][6];
  #pragma unroll
  for (int p = 0; p < 4; ++p) {
    const float* gxt = gxb + (size_t)p * GG;
    #pragma unroll
    for (int rr = 0; rr < 6; ++rr) gxr[p][rr] = gxt[rows[rr]];
  }

  __syncthreads();

  #pragma unroll 1
  for (int t4 = 0; t4 < TT; t4 += 4) {
    #pragma unroll
    for (int s = 0; s < 4; ++s) {           // fully unrolled: all gxr idx static
      const int t = t4 + s;
      const int cur = s & 1, nxt = cur ^ 1; // t4 is even, so t&1 == s&1

      // read my h chunk (32 floats) + my two h_old scalars from LDS
      float hv[32];
      {
        const float4* hp = reinterpret_cast<const float4*>(&hbuf[cur][c * 36]);
        #pragma unroll
        for (int kq = 0; kq < 8; ++kq) {
          float4 v = hp[kq];
          hv[kq * 4 + 0] = v.x; hv[kq * 4 + 1] = v.y;
          hv[kq * 4 + 2] = v.z; hv[kq * 4 + 3] = v.w;
        }
      }
      const float hold0 = hbuf[cur][hoff0];
      const float hold1 = hbuf[cur][hoff1];

      // 6 partial dot products over this 32-wide chunk
      float a0 = 0.f, a1 = 0.f, a2 = 0.f, a3 = 0.f, a4 = 0.f, a5 = 0.f;
      #pragma unroll
      for (int kk = 0; kk < 32; ++kk) {
        const float h = hv[kk];
        a0 = fmaf(w[0][kk], h, a0);
        a1 = fmaf(w[1][kk], h, a1);
        a2 = fmaf(w[2][kk], h, a2);
        a3 = fmaf(w[3][kk], h, a3);
        a4 = fmaf(w[4][kk], h, a4);
        a5 = fmaf(w[5][kk], h, a5);
      }

      // butterfly across the 4 chunk lanes (quad_perm DPP)
      a0 = quad_add<0xB1>(a0); a0 = quad_add<0x4E>(a0);
      a1 = quad_add<0xB1>(a1); a1 = quad_add<0x4E>(a1);
      a2 = quad_add<0xB1>(a2); a2 = quad_add<0x4E>(a2);
      a3 = quad_add<0xB1>(a3); a3 = quad_add<0x4E>(a3);
      a4 = quad_add<0xB1>(a4); a4 = quad_add<0x4E>(a4);
      a5 = quad_add<0xB1>(a5); a5 = quad_add<0x4E>(a5);

      // gates (PyTorch order r,z,n; bhh_n inside r*(.))
      const float r0 = sigmf(gxr[s][0] + a0 + bh[0]);
      const float z0 = sigmf(gxr[s][1] + a1 + bh[1]);
      const float n0 = tanh_fast(gxr[s][2] + r0 * (a2 + bh[2]));
      const float h0 = (1.0f - z0) * n0 + z0 * hold0;

      const float r1 = sigmf(gxr[s][3] + a3 + bh[3]);
      const float z1 = sigmf(gxr[s][4] + a4 + bh[4]);
      const float n1 = tanh_fast(gxr[s][5] + r1 * (a5 + bh[5]));
      const float h1v = (1.0f - z1) * n1 + z1 * hold1;

      if (c == 0) {
        float* ho = houtb + (size_t)t * ldh;
        ho[j0] = h0;
        ho[j1] = h1v;
        hbuf[nxt][hoff0] = h0;
        hbuf[nxt][hoff1] = h1v;
      }

      // refill slot s with gx[t+4] (clamped tail; redundant loads harmless)
      {
        const int tp = (t + 4 < TT) ? (t + 4) : (TT - 1);
        const float* gxt = gxb + (size_t)tp * GG;
        #pragma unroll
        for (int rr = 0; rr < 6; ++rr) gxr[s][rr] = gxt[rows[rr]];
      }

      wg_barrier_lds();
    }
  }
}

// ---------------------------------------------------------------------------
// Generic tiled GEMM: C[M,N] = A[M,K] * Bw[N,K]^T + bias (optional ReLU).
// 64x64 tile, K staged in 64-chunks (zero-padded), 256 threads, 4x4 per thread.
// ---------------------------------------------------------------------------
template <bool RELU>
__global__ __launch_bounds__(256) void gemm_bias(
    const float* __restrict__ A, int lda,
    const float* __restrict__ Bw,       // [N, K] row-major
    const float* __restrict__ bias,     // [N]
    float* __restrict__ C, int ldc,
    int M, int N, int K)
{
  __shared__ float As[64][65];
  __shared__ float Bs[64][65];

  const int tid = threadIdx.x;
  const int tx = tid & 15, ty = tid >> 4;
  const int row0 = blockIdx.x * 64, col0 = blockIdx.y * 64;

  float acc[4][4] = {};

  for (int k0 = 0; k0 < K; k0 += 64) {
    const int kc = (K - k0 < 64) ? (K - k0) : 64;

    #pragma unroll
    for (int l = 0; l < 16; ++l) {
      const int idx = tid + l * 256;
      const int r = idx >> 6, cc = idx & 63;
      As[r][cc] = (cc < kc) ? A[(size_t)(row0 + r) * lda + k0 + cc] : 0.0f;
      const int n = col0 + r;
      Bs[r][cc] = (cc < kc && n < N) ? Bw[(size_t)n * K + k0 + cc] : 0.0f;
    }
    __syncthreads();

    #pragma unroll 8
    for (int kk = 0; kk < 64; ++kk) {
      float av[4], bv[4];
      #pragma unroll
      for (int i = 0; i < 4; ++i) av[i] = As[ty * 4 + i][kk];
      #pragma unroll
      for (int j = 0; j < 4; ++j) bv[j] = Bs[tx * 4 + j][kk];
      #pragma unroll
      for (int i = 0; i < 4; ++i)
        #pragma unroll
        for (int j = 0; j < 4; ++j)
          acc[i][j] = fmaf(av[i], bv[j], acc[i][j]);
    }
    __syncthreads();
  }

  #pragma unroll
  for (int i = 0; i < 4; ++i) {
    const int r = row0 + ty * 4 + i;
    #pragma unroll
    for (int j = 0; j < 4; ++j) {
      const int cn = col0 + tx * 4 + j;
      if (cn < N) {
        float v = acc[i][j] + bias[cn];
        if (RELU) v = (v > 0.0f) ? v : 0.0f;
        C[(size_t)r * ldc + cn] = v;
      }
    }
  }
}

// ---------------------------------------------------------------------------
extern "C" void kernel_launch(void* const* d_in, const int* in_sizes, int n_in,
                              void* d_out, int out_size, void* d_ws, size_t ws_size,
                              hipStream_t stream) {
  const float* x    = (const float*)d_in[0];
  const float* Wih0 = (const float*)d_in[1];
  const float* Whh0 = (const float*)d_in[2];
  const float* bih0 = (const float*)d_in[3];
  const float* bhh0 = (const float*)d_in[4];
  const float* Wih1 = (const float*)d_in[5];
  const float* Whh1 = (const float*)d_in[6];
  const float* bih1 = (const float*)d_in[7];
  const float* bhh1 = (const float*)d_in[8];
  const float* W1   = (const float*)d_in[9];
  const float* b1   = (const float*)d_in[10];
  const float* W2   = (const float*)d_in[11];
  const float* b2   = (const float*)d_in[12];
  float* out = (float*)d_out;

  const int M = BB * TT;  // 256000 rows
  float* gxbuf = (float*)d_ws;                       // M*384 floats
  float* h1buf = gxbuf + (size_t)M * GG;             // M*128 floats

  dim3 blk(256);

  // 1) gx0 = x @ Wih0^T + bih0
  gemm_bias<false><<<dim3(M / 64, 6), blk, 0, stream>>>(
      x, 26, Wih0, bih0, gxbuf, GG, M, GG, 26);

  // 2) layer-0 recurrence -> h1buf
  gru_rec<<<dim3(BB), blk, 0, stream>>>(gxbuf, Whh0, bhh0, h1buf, HH);

  // 3) gx1 = h1 @ Wih1^T + bih1 (reuse gxbuf)
  gemm_bias<false><<<dim3(M / 64, 6), blk, 0, stream>>>(
      h1buf, HH, Wih1, bih1, gxbuf, GG, M, GG, HH);

  // 4) layer-1 recurrence -> h2 in d_out rows (stride 136)
  gru_rec<<<dim3(BB), blk, 0, stream>>>(gxbuf, Whh1, bhh1, out, 136);

  // 5) hidden = relu(h2 @ W1^T + b1) -> h1buf
  gemm_bias<true><<<dim3(M / 64, 2), blk, 0, stream>>>(
      out, 136, W1, b1, h1buf, HH, M, HH, HH);

  // 6) out = hidden @ W2^T + b2 -> d_out
  gemm_bias<false><<<dim3(M / 64, 3), blk, 0, stream>>>(
      h1buf, HH, W2, b2, out, 136, M, 136, HH);
}

// Round 3
// 6361.876 us; speedup vs baseline: 1.3686x; 1.3049x over previous
//
#include <hip/hip_runtime.h>
#include <cstdint>

#define HH 128
#define GG 384   // 3H
#define TT 4000
#define BB 64

__device__ __forceinline__ float sigmf(float x) {
  return 1.0f / (1.0f + __expf(-x));
}
__device__ __forceinline__ float tanh_fast(float x) {
  return 2.0f / (1.0f + __expf(-2.0f * x)) - 1.0f;
}

template <int CTRL>
__device__ __forceinline__ float quad_add(float x) {
  int y = __builtin_amdgcn_mov_dpp(__float_as_int(x), CTRL, 0xF, 0xF, true);
  return x + __int_as_float(y);
}

// LDS-only barrier: do NOT drain vmcnt (keeps global prefetch in flight).
__device__ __forceinline__ void wg_barrier_lds() {
  asm volatile("s_waitcnt lgkmcnt(0)" ::: "memory");
  __builtin_amdgcn_s_barrier();
  asm volatile("" ::: "memory");
}

// ---------------------------------------------------------------------------
// GRU recurrence: one block per batch element, 512 threads = 128 quads x 4
// k-chunks = 8 waves (2/SIMD). Thread (q,c) owns 3 rows of Whh (r,z,n for
// j=q), k-range [32c,32c+32) -- 96 weight VGPRs, pinned via asm so the
// compiler cannot sink the loads into the loop (round-2 failure: VGPR=136
// proved w was reloaded from L2 every step -> ~880cy/step L2 BW).
// h double-buffered in LDS; gx register-prefetched 4 steps ahead; per-step
// barrier drains lgkmcnt only.
// ---------------------------------------------------------------------------
__global__ __launch_bounds__(512, 2) void gru_rec(
    const float* __restrict__ gx,   // [B, T, 384] input contributions (bih included)
    const float* __restrict__ Whh,  // [384, 128]
    const float* __restrict__ bhh,  // [384]
    float* __restrict__ hout,       // [B, T, ldh]
    int ldh)
{
  __shared__ float hbuf[2][144];

  const int tid = threadIdx.x;
  const int q = tid >> 2;   // 0..127 : hidden index j
  const int c = tid & 3;    // k-chunk
  const int b = blockIdx.x;

  const int rows[3] = { q, q + 128, q + 256 };

  // Whh rows (this thread's k-chunk) -> registers, then pin.
  float w[3][32];
  #pragma unroll
  for (int rr = 0; rr < 3; ++rr) {
    const float4* wp = reinterpret_cast<const float4*>(Whh + (size_t)rows[rr] * HH + c * 32);
    #pragma unroll
    for (int kq = 0; kq < 8; ++kq) {
      float4 v = wp[kq];
      w[rr][kq * 4 + 0] = v.x; w[rr][kq * 4 + 1] = v.y;
      w[rr][kq * 4 + 2] = v.z; w[rr][kq * 4 + 3] = v.w;
    }
  }
  #pragma unroll
  for (int rr = 0; rr < 3; ++rr)
    #pragma unroll
    for (int kk = 0; kk < 32; ++kk)
      asm volatile("" : "+v"(w[rr][kk]));   // opaque: no remat of the load

  float bh[3];
  #pragma unroll
  for (int rr = 0; rr < 3; ++rr) bh[rr] = bhh[rows[rr]];

  for (int i = tid; i < 2 * 144; i += 512) (&hbuf[0][0])[i] = 0.0f;

  const float* gxb = gx + (size_t)b * TT * GG;
  float* houtb = hout + (size_t)b * TT * ldh;

  const int hoff = ((q >> 5) * 36) + (q & 31);

  // prefetch gx for t = 0..3 (depth-4 rotating register buffer)
  float gxr[4][3];
  #pragma unroll
  for (int p = 0; p < 4; ++p) {
    const float* gxt = gxb + (size_t)p * GG;
    #pragma unroll
    for (int rr = 0; rr < 3; ++rr) gxr[p][rr] = gxt[rows[rr]];
  }

  __syncthreads();

  #pragma unroll 1
  for (int t4 = 0; t4 < TT; t4 += 4) {
    #pragma unroll
    for (int s = 0; s < 4; ++s) {           // fully unrolled: all gxr idx static
      const int t = t4 + s;
      const int cur = s & 1, nxt = cur ^ 1; // t4 even => t&1 == s&1

      // read my h chunk (32 floats) + my h_old scalar from LDS
      float hv[32];
      {
        const float4* hp = reinterpret_cast<const float4*>(&hbuf[cur][c * 36]);
        #pragma unroll
        for (int kq = 0; kq < 8; ++kq) {
          float4 v = hp[kq];
          hv[kq * 4 + 0] = v.x; hv[kq * 4 + 1] = v.y;
          hv[kq * 4 + 2] = v.z; hv[kq * 4 + 3] = v.w;
        }
      }
      const float hold = hbuf[cur][hoff];

      // 3 partial dot products over this 32-wide chunk
      float a0 = 0.f, a1 = 0.f, a2 = 0.f;
      #pragma unroll
      for (int kk = 0; kk < 32; ++kk) {
        const float h = hv[kk];
        a0 = fmaf(w[0][kk], h, a0);
        a1 = fmaf(w[1][kk], h, a1);
        a2 = fmaf(w[2][kk], h, a2);
      }

      // butterfly across the 4 chunk lanes (quad_perm DPP)
      a0 = quad_add<0xB1>(a0); a0 = quad_add<0x4E>(a0);
      a1 = quad_add<0xB1>(a1); a1 = quad_add<0x4E>(a1);
      a2 = quad_add<0xB1>(a2); a2 = quad_add<0x4E>(a2);

      // gates (PyTorch order r,z,n; bhh_n inside r*(.))
      const float r = sigmf(gxr[s][0] + a0 + bh[0]);
      const float z = sigmf(gxr[s][1] + a1 + bh[1]);
      const float n = tanh_fast(gxr[s][2] + r * (a2 + bh[2]));
      const float h = (1.0f - z) * n + z * hold;

      if (c == 0) {
        houtb[(size_t)t * ldh + q] = h;
        hbuf[nxt][hoff] = h;
      }

      // refill slot s with gx[t+4] (clamped tail; redundant loads harmless)
      {
        const int tp = (t + 4 < TT) ? (t + 4) : (TT - 1);
        const float* gxt = gxb + (size_t)tp * GG;
        #pragma unroll
        for (int rr = 0; rr < 3; ++rr) gxr[s][rr] = gxt[rows[rr]];
      }

      wg_barrier_lds();
    }
  }
}

// ---------------------------------------------------------------------------
// Tiled GEMM, K a compile-time constant: C[M,N] = A[M,K] * Bw[N,K]^T + bias.
// 64x64 tile, 256 threads, 4x4 per thread. Inner loop trip = exact K chunk
// (K=26 runs 26 iters, not 64 zero-padded).
// ---------------------------------------------------------------------------
template <int K, bool RELU>
__global__ __launch_bounds__(256) void gemm_bias(
    const float* __restrict__ A, int lda,
    const float* __restrict__ Bw,       // [N, K] row-major
    const float* __restrict__ bias,     // [N]
    float* __restrict__ C, int ldc,
    int M, int N)
{
  __shared__ float As[64][65];
  __shared__ float Bs[64][65];

  const int tid = threadIdx.x;
  const int tx = tid & 15, ty = tid >> 4;
  const int row0 = blockIdx.x * 64, col0 = blockIdx.y * 64;

  float acc[4][4] = {};

  #pragma unroll
  for (int k0 = 0; k0 < K; k0 += 64) {
    const int kc = (K - k0 < 64) ? (K - k0) : 64;   // constant-folds per k0

    #pragma unroll
    for (int l = 0; l < 16; ++l) {
      const int idx = tid + l * 256;
      const int r = idx >> 6, cc = idx & 63;
      As[r][cc] = (cc < kc) ? A[(size_t)(row0 + r) * lda + k0 + cc] : 0.0f;
      const int n = col0 + r;
      Bs[r][cc] = (cc < kc && n < N) ? Bw[(size_t)n * K + k0 + cc] : 0.0f;
    }
    __syncthreads();

    #pragma unroll 13
    for (int kk = 0; kk < kc; ++kk) {
      float av[4], bv[4];
      #pragma unroll
      for (int i = 0; i < 4; ++i) av[i] = As[ty * 4 + i][kk];
      #pragma unroll
      for (int j = 0; j < 4; ++j) bv[j] = Bs[tx * 4 + j][kk];
      #pragma unroll
      for (int i = 0; i < 4; ++i)
        #pragma unroll
        for (int j = 0; j < 4; ++j)
          acc[i][j] = fmaf(av[i], bv[j], acc[i][j]);
    }
    __syncthreads();
  }

  #pragma unroll
  for (int i = 0; i < 4; ++i) {
    const int r = row0 + ty * 4 + i;
    #pragma unroll
    for (int j = 0; j < 4; ++j) {
      const int cn = col0 + tx * 4 + j;
      if (cn < N) {
        float v = acc[i][j] + bias[cn];
        if (RELU) v = (v > 0.0f) ? v : 0.0f;
        C[(size_t)r * ldc + cn] = v;
      }
    }
  }
}

// ---------------------------------------------------------------------------
extern "C" void kernel_launch(void* const* d_in, const int* in_sizes, int n_in,
                              void* d_out, int out_size, void* d_ws, size_t ws_size,
                              hipStream_t stream) {
  const float* x    = (const float*)d_in[0];
  const float* Wih0 = (const float*)d_in[1];
  const float* Whh0 = (const float*)d_in[2];
  const float* bih0 = (const float*)d_in[3];
  const float* bhh0 = (const float*)d_in[4];
  const float* Wih1 = (const float*)d_in[5];
  const float* Whh1 = (const float*)d_in[6];
  const float* bih1 = (const float*)d_in[7];
  const float* bhh1 = (const float*)d_in[8];
  const float* W1   = (const float*)d_in[9];
  const float* b1   = (const float*)d_in[10];
  const float* W2   = (const float*)d_in[11];
  const float* b2   = (const float*)d_in[12];
  float* out = (float*)d_out;

  const int M = BB * TT;  // 256000 rows
  float* gxbuf = (float*)d_ws;                       // M*384 floats
  float* h1buf = gxbuf + (size_t)M * GG;             // M*128 floats

  // 1) gx0 = x @ Wih0^T + bih0   (K=26 exact)
  gemm_bias<26, false><<<dim3(M / 64, 6), dim3(256), 0, stream>>>(
      x, 26, Wih0, bih0, gxbuf, GG, M, GG);

  // 2) layer-0 recurrence -> h1buf
  gru_rec<<<dim3(BB), dim3(512), 0, stream>>>(gxbuf, Whh0, bhh0, h1buf, HH);

  // 3) gx1 = h1 @ Wih1^T + bih1 (reuse gxbuf)
  gemm_bias<128, false><<<dim3(M / 64, 6), dim3(256), 0, stream>>>(
      h1buf, HH, Wih1, bih1, gxbuf, GG, M, GG);

  // 4) layer-1 recurrence -> h2 in d_out rows (stride 136)
  gru_rec<<<dim3(BB), dim3(512), 0, stream>>>(gxbuf, Whh1, bhh1, out, 136);

  // 5) hidden = relu(h2 @ W1^T + b1) -> h1buf
  gemm_bias<128, true><<<dim3(M / 64, 2), dim3(256), 0, stream>>>(
      out, 136, W1, b1, h1buf, HH, M, HH);

  // 6) out = hidden @ W2^T + b2 -> d_out
  gemm_bias<128, false><<<dim3(M / 64, 3), dim3(256), 0, stream>>>(
      h1buf, HH, W2, b2, out, 136, M, 136);
}

// Round 4
// 6315.755 us; speedup vs baseline: 1.3786x; 1.0073x over previous
//
#include <hip/hip_runtime.h>
#include <cstdint>

#define HH 128
#define GG 384   // 3H
#define TT 4000
#define BB 64

__device__ __forceinline__ float sigmf(float x) {
  return 1.0f / (1.0f + __expf(-x));
}
__device__ __forceinline__ float tanh_fast(float x) {
  return 2.0f / (1.0f + __expf(-2.0f * x)) - 1.0f;
}

template <int CTRL>
__device__ __forceinline__ float quad_add(float x) {
  int y = __builtin_amdgcn_mov_dpp(__float_as_int(x), CTRL, 0xF, 0xF, true);
  return x + __int_as_float(y);
}

// LDS-only barrier: do NOT drain vmcnt (keeps global prefetch in flight).
__device__ __forceinline__ void wg_barrier_lds() {
  asm volatile("s_waitcnt lgkmcnt(0)" ::: "memory");
  __builtin_amdgcn_s_barrier();
  asm volatile("" ::: "memory");
}

// ---------------------------------------------------------------------------
// GRU recurrence: one block per batch element, 512 threads = 128 quads x 4
// k-chunks = 8 waves (2/SIMD). Thread (q,c) owns 3 rows of Whh (r,z,n for
// j=q), k-range [32c,32c+32) -- 96 weight VGPRs.
//
// Round-3 lesson: VGPR_Count=76 + VALUBusy 98% (active-CU) proved the
// compiler's occupancy heuristic AGPR-spilled the w array and re-shuffled
// it every step (v_accvgpr_read bloat). amdgpu_waves_per_eu(2,2) pins the
// budget at 256 VGPRs (we only launch 64 blocks on 256 CUs -- extra
// occupancy buys nothing), so w stays in arch VGPRs.
// ---------------------------------------------------------------------------
__global__ __launch_bounds__(512)
__attribute__((amdgpu_waves_per_eu(2, 2)))
void gru_rec(
    const float* __restrict__ gx,   // [B, T, 384] input contributions (bih included)
    const float* __restrict__ Whh,  // [384, 128]
    const float* __restrict__ bhh,  // [384]
    float* __restrict__ hout,       // [B, T, ldh]
    int ldh)
{
  __shared__ float hbuf[2][144];

  const int tid = threadIdx.x;
  const int q = tid >> 2;   // 0..127 : hidden index j
  const int c = tid & 3;    // k-chunk
  const int b = blockIdx.x;

  const int rows[3] = { q, q + 128, q + 256 };

  // Whh rows (this thread's k-chunk) -> registers, then pin.
  float w[3][32];
  #pragma unroll
  for (int rr = 0; rr < 3; ++rr) {
    const float4* wp = reinterpret_cast<const float4*>(Whh + (size_t)rows[rr] * HH + c * 32);
    #pragma unroll
    for (int kq = 0; kq < 8; ++kq) {
      float4 v = wp[kq];
      w[rr][kq * 4 + 0] = v.x; w[rr][kq * 4 + 1] = v.y;
      w[rr][kq * 4 + 2] = v.z; w[rr][kq * 4 + 3] = v.w;
    }
  }
  #pragma unroll
  for (int rr = 0; rr < 3; ++rr)
    #pragma unroll
    for (int kk = 0; kk < 32; ++kk)
      asm volatile("" : "+v"(w[rr][kk]));   // opaque: no remat of the load

  float bh[3];
  #pragma unroll
  for (int rr = 0; rr < 3; ++rr) bh[rr] = bhh[rows[rr]];

  for (int i = tid; i < 2 * 144; i += 512) (&hbuf[0][0])[i] = 0.0f;

  const float* gxb = gx + (size_t)b * TT * GG;
  float* houtb = hout + (size_t)b * TT * ldh;

  const int hoff = ((q >> 5) * 36) + (q & 31);

  // prefetch gx for t = 0..3 (depth-4 rotating register buffer)
  float gxr[4][3];
  #pragma unroll
  for (int p = 0; p < 4; ++p) {
    const float* gxt = gxb + (size_t)p * GG;
    #pragma unroll
    for (int rr = 0; rr < 3; ++rr) gxr[p][rr] = gxt[rows[rr]];
  }

  __syncthreads();

  #pragma unroll 1
  for (int t4 = 0; t4 < TT; t4 += 4) {
    #pragma unroll
    for (int s = 0; s < 4; ++s) {           // fully unrolled: all gxr idx static
      const int t = t4 + s;
      const int cur = s & 1, nxt = cur ^ 1; // t4 even => t&1 == s&1

      // read my h chunk (32 floats) + my h_old scalar from LDS
      float hv[32];
      {
        const float4* hp = reinterpret_cast<const float4*>(&hbuf[cur][c * 36]);
        #pragma unroll
        for (int kq = 0; kq < 8; ++kq) {
          float4 v = hp[kq];
          hv[kq * 4 + 0] = v.x; hv[kq * 4 + 1] = v.y;
          hv[kq * 4 + 2] = v.z; hv[kq * 4 + 3] = v.w;
        }
      }
      const float hold = hbuf[cur][hoff];

      // 3 partial dot products over this 32-wide chunk
      float a0 = 0.f, a1 = 0.f, a2 = 0.f;
      #pragma unroll
      for (int kk = 0; kk < 32; ++kk) {
        const float h = hv[kk];
        a0 = fmaf(w[0][kk], h, a0);
        a1 = fmaf(w[1][kk], h, a1);
        a2 = fmaf(w[2][kk], h, a2);
      }

      // butterfly across the 4 chunk lanes (quad_perm DPP)
      a0 = quad_add<0xB1>(a0); a0 = quad_add<0x4E>(a0);
      a1 = quad_add<0xB1>(a1); a1 = quad_add<0x4E>(a1);
      a2 = quad_add<0xB1>(a2); a2 = quad_add<0x4E>(a2);

      // gates (PyTorch order r,z,n; bhh_n inside r*(.))
      const float r = sigmf(gxr[s][0] + a0 + bh[0]);
      const float z = sigmf(gxr[s][1] + a1 + bh[1]);
      const float n = tanh_fast(gxr[s][2] + r * (a2 + bh[2]));
      const float h = (1.0f - z) * n + z * hold;

      if (c == 0) {
        houtb[(size_t)t * ldh + q] = h;
        hbuf[nxt][hoff] = h;
      }

      // refill slot s with gx[t+4] (clamped tail; redundant loads harmless)
      {
        const int tp = (t + 4 < TT) ? (t + 4) : (TT - 1);
        const float* gxt = gxb + (size_t)tp * GG;
        #pragma unroll
        for (int rr = 0; rr < 3; ++rr) gxr[s][rr] = gxt[rows[rr]];
      }

      wg_barrier_lds();
    }
  }
}

// ---------------------------------------------------------------------------
// Tiled GEMM, K a compile-time constant: C[M,N] = A[M,K] * Bw[N,K]^T + bias.
// 64x64 tile, 256 threads, 4x4 per thread. Inner loop trip = exact K chunk
// (K=26 runs 26 iters, not 64 zero-padded).
// ---------------------------------------------------------------------------
template <int K, bool RELU>
__global__ __launch_bounds__(256) void gemm_bias(
    const float* __restrict__ A, int lda,
    const float* __restrict__ Bw,       // [N, K] row-major
    const float* __restrict__ bias,     // [N]
    float* __restrict__ C, int ldc,
    int M, int N)
{
  __shared__ float As[64][65];
  __shared__ float Bs[64][65];

  const int tid = threadIdx.x;
  const int tx = tid & 15, ty = tid >> 4;
  const int row0 = blockIdx.x * 64, col0 = blockIdx.y * 64;

  float acc[4][4] = {};

  #pragma unroll
  for (int k0 = 0; k0 < K; k0 += 64) {
    const int kc = (K - k0 < 64) ? (K - k0) : 64;   // constant-folds per k0

    #pragma unroll
    for (int l = 0; l < 16; ++l) {
      const int idx = tid + l * 256;
      const int r = idx >> 6, cc = idx & 63;
      As[r][cc] = (cc < kc) ? A[(size_t)(row0 + r) * lda + k0 + cc] : 0.0f;
      const int n = col0 + r;
      Bs[r][cc] = (cc < kc && n < N) ? Bw[(size_t)n * K + k0 + cc] : 0.0f;
    }
    __syncthreads();

    #pragma unroll 13
    for (int kk = 0; kk < kc; ++kk) {
      float av[4], bv[4];
      #pragma unroll
      for (int i = 0; i < 4; ++i) av[i] = As[ty * 4 + i][kk];
      #pragma unroll
      for (int j = 0; j < 4; ++j) bv[j] = Bs[tx * 4 + j][kk];
      #pragma unroll
      for (int i = 0; i < 4; ++i)
        #pragma unroll
        for (int j = 0; j < 4; ++j)
          acc[i][j] = fmaf(av[i], bv[j], acc[i][j]);
    }
    __syncthreads();
  }

  #pragma unroll
  for (int i = 0; i < 4; ++i) {
    const int r = row0 + ty * 4 + i;
    #pragma unroll
    for (int j = 0; j < 4; ++j) {
      const int cn = col0 + tx * 4 + j;
      if (cn < N) {
        float v = acc[i][j] + bias[cn];
        if (RELU) v = (v > 0.0f) ? v : 0.0f;
        C[(size_t)r * ldc + cn] = v;
      }
    }
  }
}

// ---------------------------------------------------------------------------
extern "C" void kernel_launch(void* const* d_in, const int* in_sizes, int n_in,
                              void* d_out, int out_size, void* d_ws, size_t ws_size,
                              hipStream_t stream) {
  const float* x    = (const float*)d_in[0];
  const float* Wih0 = (const float*)d_in[1];
  const float* Whh0 = (const float*)d_in[2];
  const float* bih0 = (const float*)d_in[3];
  const float* bhh0 = (const float*)d_in[4];
  const float* Wih1 = (const float*)d_in[5];
  const float* Whh1 = (const float*)d_in[6];
  const float* bih1 = (const float*)d_in[7];
  const float* bhh1 = (const float*)d_in[8];
  const float* W1   = (const float*)d_in[9];
  const float* b1   = (const float*)d_in[10];
  const float* W2   = (const float*)d_in[11];
  const float* b2   = (const float*)d_in[12];
  float* out = (float*)d_out;

  const int M = BB * TT;  // 256000 rows
  float* gxbuf = (float*)d_ws;                       // M*384 floats
  float* h1buf = gxbuf + (size_t)M * GG;             // M*128 floats

  // 1) gx0 = x @ Wih0^T + bih0   (K=26 exact)
  gemm_bias<26, false><<<dim3(M / 64, 6), dim3(256), 0, stream>>>(
      x, 26, Wih0, bih0, gxbuf, GG, M, GG);

  // 2) layer-0 recurrence -> h1buf
  gru_rec<<<dim3(BB), dim3(512), 0, stream>>>(gxbuf, Whh0, bhh0, h1buf, HH);

  // 3) gx1 = h1 @ Wih1^T + bih1 (reuse gxbuf)
  gemm_bias<128, false><<<dim3(M / 64, 6), dim3(256), 0, stream>>>(
      h1buf, HH, Wih1, bih1, gxbuf, GG, M, GG);

  // 4) layer-1 recurrence -> h2 in d_out rows (stride 136)
  gru_rec<<<dim3(BB), dim3(512), 0, stream>>>(gxbuf, Whh1, bhh1, out, 136);

  // 5) hidden = relu(h2 @ W1^T + b1) -> h1buf
  gemm_bias<128, true><<<dim3(M / 64, 2), dim3(256), 0, stream>>>(
      out, 136, W1, b1, h1buf, HH, M, HH);

  // 6) out = hidden @ W2^T + b2 -> d_out
  gemm_bias<128, false><<<dim3(M / 64, 3), dim3(256), 0, stream>>>(
      h1buf, HH, W2, b2, out, 136, M, 136);
}

// Round 5
// 6247.964 us; speedup vs baseline: 1.3935x; 1.0109x over previous
//
#include <hip/hip_runtime.h>
#include <hip/hip_fp16.h>
#include <cstdint>

#define HH 128
#define GG 384   // 3H
#define TT 4000
#define BB 64

typedef uint32_t u32;

__device__ __forceinline__ float sigmf(float x) {
  return __fdividef(1.0f, 1.0f + __expf(-x));
}
__device__ __forceinline__ float tanh_fast(float x) {
  return __fdividef(2.0f, 1.0f + __expf(-2.0f * x)) - 1.0f;
}

template <int CTRL>
__device__ __forceinline__ float quad_add(float x) {
  int y = __builtin_amdgcn_mov_dpp(__float_as_int(x), CTRL, 0xF, 0xF, true);
  return x + __int_as_float(y);
}

// v_dot2_f32_f16: d = a.x*b.x + a.y*b.y + c  (fp16 mul exact into fp32 acc)
__device__ __forceinline__ float fdot2(u32 a, u32 b, float c) {
  float d;
  asm("v_dot2_f32_f16 %0, %1, %2, %3" : "=v"(d) : "v"(a), "v"(b), "v"(c));
  return d;
}

__device__ __forceinline__ u32 packh2(float a, float b) {
  __half2 h = __floats2half2_rn(a, b);
  union { __half2 h; u32 u; } cv;
  cv.h = h;
  return cv.u;
}

// LDS-only barrier: do NOT drain vmcnt (keeps global prefetch in flight).
__device__ __forceinline__ void wg_barrier_lds() {
  asm volatile("s_waitcnt lgkmcnt(0)" ::: "memory");
  __builtin_amdgcn_s_barrier();
  asm volatile("" ::: "memory");
}

// ---------------------------------------------------------------------------
// GRU recurrence, fp16-dot2 edition. One block per batch element, 512
// threads = 128 q x 4 c = 8 waves. Thread (q,c) owns gate rows {q, q+128,
// q+256} of Whh for k in [32c,32c+32), packed as 48 half2 in VGPRs.
// h is kept packed-half2 in LDS (read as 4x ds_read_b128, 16-way broadcast);
// h_old stays fp32 in a register (all 4 quad lanes compute h redundantly).
// 48 v_dot2_f32_f16 per step replace 96 fp32 FMAs; quantization is only on
// w,h inputs (2^-11) -> gate preact err ~2e-4, final absmax ~1e-3.
//
// Rounds 2-4 lesson: ~140+ live fp32 regs/thread made the allocator AGPR-
// spill the weight array (constant 2.45x VALU bloat). This design's live set
// (~100) fits any budget -> nothing to spill.
// ---------------------------------------------------------------------------
__global__ __launch_bounds__(512) void gru_rec(
    const float* __restrict__ gx,   // [B, T, 384] input contributions (bih included)
    const float* __restrict__ Whh,  // [384, 128]
    const float* __restrict__ bhh,  // [384]
    float* __restrict__ hout,       // [B, T, ldh]
    int ldh)
{
  // h as packed half2: 2 buffers x 4 chunks x (16 used + 4 pad) u32
  __shared__ u32 hlds[2][80];

  const int tid = threadIdx.x;
  const int q = tid >> 2;   // 0..127 : hidden index j
  const int c = tid & 3;    // k-chunk
  const int b = blockIdx.x;

  const int rows[3] = { q, q + 128, q + 256 };

  // Whh rows (this thread's k-chunk) -> packed half2 registers
  u32 wz[3][16];
  #pragma unroll
  for (int rr = 0; rr < 3; ++rr) {
    const float4* wp = reinterpret_cast<const float4*>(Whh + (size_t)rows[rr] * HH + c * 32);
    #pragma unroll
    for (int p = 0; p < 8; ++p) {
      float4 v = wp[p];
      wz[rr][p * 2 + 0] = packh2(v.x, v.y);
      wz[rr][p * 2 + 1] = packh2(v.z, v.w);
    }
  }

  float bh[3];
  #pragma unroll
  for (int rr = 0; rr < 3; ++rr) bh[rr] = bhh[rows[rr]];

  for (int i = tid; i < 2 * 80; i += 512) (&hlds[0][0])[i] = 0u;

  const float* gxb = gx + (size_t)b * TT * GG;
  float* houtb = hout + (size_t)b * TT * ldh;

  float hprev = 0.0f;   // fp32 h state for my q (identical across the quad)

  // prefetch gx for t = 0..3 (depth-4 rotating register buffer)
  float gxr[4][3];
  #pragma unroll
  for (int p = 0; p < 4; ++p) {
    const float* gxt = gxb + (size_t)p * GG;
    #pragma unroll
    for (int rr = 0; rr < 3; ++rr) gxr[p][rr] = gxt[rows[rr]];
  }

  __syncthreads();

  #pragma unroll 1
  for (int t4 = 0; t4 < TT; t4 += 4) {
    #pragma unroll
    for (int s = 0; s < 4; ++s) {           // fully unrolled: all indices static
      const int t = t4 + s;
      const int cur = s & 1, nxt = cur ^ 1; // t4 even => t&1 == s&1

      // read my h chunk: 16 half2 via 4x ds_read_b128 (16-way broadcast)
      u32 hv[16];
      {
        const uint4* hp = reinterpret_cast<const uint4*>(&hlds[cur][c * 20]);
        #pragma unroll
        for (int p = 0; p < 4; ++p) {
          uint4 v = hp[p];
          hv[p * 4 + 0] = v.x; hv[p * 4 + 1] = v.y;
          hv[p * 4 + 2] = v.z; hv[p * 4 + 3] = v.w;
        }
      }

      // 3 gate dots, 2 independent chains each (12 chains across 2 waves/SIMD)
      float a0 = 0.f, a1 = 0.f, a2 = 0.f;
      float b0 = 0.f, b1 = 0.f, b2 = 0.f;
      #pragma unroll
      for (int p = 0; p < 16; p += 2) {
        a0 = fdot2(hv[p], wz[0][p], a0);
        a1 = fdot2(hv[p], wz[1][p], a1);
        a2 = fdot2(hv[p], wz[2][p], a2);
        b0 = fdot2(hv[p + 1], wz[0][p + 1], b0);
        b1 = fdot2(hv[p + 1], wz[1][p + 1], b1);
        b2 = fdot2(hv[p + 1], wz[2][p + 1], b2);
      }
      a0 += b0; a1 += b1; a2 += b2;

      // butterfly across the 4 chunk lanes (quad_perm DPP)
      a0 = quad_add<0xB1>(a0); a0 = quad_add<0x4E>(a0);
      a1 = quad_add<0xB1>(a1); a1 = quad_add<0x4E>(a1);
      a2 = quad_add<0xB1>(a2); a2 = quad_add<0x4E>(a2);

      // gates (PyTorch order r,z,n; bhh_n inside r*(.))
      const float r = sigmf(gxr[s][0] + a0 + bh[0]);
      const float z = sigmf(gxr[s][1] + a1 + bh[1]);
      const float n = tanh_fast(gxr[s][2] + r * (a2 + bh[2]));
      const float h = (1.0f - z) * n + z * hprev;
      hprev = h;

      if (c == 0) {
        houtb[(size_t)t * ldh + q] = h;
        // packed half write of my h into next buffer
        __half* hw = reinterpret_cast<__half*>(&hlds[nxt][(q >> 5) * 20]);
        hw[q & 31] = __float2half_rn(h);
      }

      // refill gx slot s with t+4 (clamped tail; redundant loads harmless)
      {
        const int tp = (t + 4 < TT) ? (t + 4) : (TT - 1);
        const float* gxt = gxb + (size_t)tp * GG;
        #pragma unroll
        for (int rr = 0; rr < 3; ++rr) gxr[s][rr] = gxt[rows[rr]];
      }

      wg_barrier_lds();
    }
  }
}

// ---------------------------------------------------------------------------
// Tiled GEMM, K a compile-time constant: C[M,N] = A[M,K] * Bw[N,K]^T + bias.
// 64x64 tile, 256 threads, 4x4 per thread.
// ---------------------------------------------------------------------------
template <int K, bool RELU>
__global__ __launch_bounds__(256) void gemm_bias(
    const float* __restrict__ A, int lda,
    const float* __restrict__ Bw,       // [N, K] row-major
    const float* __restrict__ bias,     // [N]
    float* __restrict__ C, int ldc,
    int M, int N)
{
  __shared__ float As[64][65];
  __shared__ float Bs[64][65];

  const int tid = threadIdx.x;
  const int tx = tid & 15, ty = tid >> 4;
  const int row0 = blockIdx.x * 64, col0 = blockIdx.y * 64;

  float acc[4][4] = {};

  #pragma unroll
  for (int k0 = 0; k0 < K; k0 += 64) {
    const int kc = (K - k0 < 64) ? (K - k0) : 64;

    #pragma unroll
    for (int l = 0; l < 16; ++l) {
      const int idx = tid + l * 256;
      const int r = idx >> 6, cc = idx & 63;
      As[r][cc] = (cc < kc) ? A[(size_t)(row0 + r) * lda + k0 + cc] : 0.0f;
      const int n = col0 + r;
      Bs[r][cc] = (cc < kc && n < N) ? Bw[(size_t)n * K + k0 + cc] : 0.0f;
    }
    __syncthreads();

    #pragma unroll 13
    for (int kk = 0; kk < kc; ++kk) {
      float av[4], bv[4];
      #pragma unroll
      for (int i = 0; i < 4; ++i) av[i] = As[ty * 4 + i][kk];
      #pragma unroll
      for (int j = 0; j < 4; ++j) bv[j] = Bs[tx * 4 + j][kk];
      #pragma unroll
      for (int i = 0; i < 4; ++i)
        #pragma unroll
        for (int j = 0; j < 4; ++j)
          acc[i][j] = fmaf(av[i], bv[j], acc[i][j]);
    }
    __syncthreads();
  }

  #pragma unroll
  for (int i = 0; i < 4; ++i) {
    const int r = row0 + ty * 4 + i;
    #pragma unroll
    for (int j = 0; j < 4; ++j) {
      const int cn = col0 + tx * 4 + j;
      if (cn < N) {
        float v = acc[i][j] + bias[cn];
        if (RELU) v = (v > 0.0f) ? v : 0.0f;
        C[(size_t)r * ldc + cn] = v;
      }
    }
  }
}

// ---------------------------------------------------------------------------
extern "C" void kernel_launch(void* const* d_in, const int* in_sizes, int n_in,
                              void* d_out, int out_size, void* d_ws, size_t ws_size,
                              hipStream_t stream) {
  const float* x    = (const float*)d_in[0];
  const float* Wih0 = (const float*)d_in[1];
  const float* Whh0 = (const float*)d_in[2];
  const float* bih0 = (const float*)d_in[3];
  const float* bhh0 = (const float*)d_in[4];
  const float* Wih1 = (const float*)d_in[5];
  const float* Whh1 = (const float*)d_in[6];
  const float* bih1 = (const float*)d_in[7];
  const float* bhh1 = (const float*)d_in[8];
  const float* W1   = (const float*)d_in[9];
  const float* b1   = (const float*)d_in[10];
  const float* W2   = (const float*)d_in[11];
  const float* b2   = (const float*)d_in[12];
  float* out = (float*)d_out;

  const int M = BB * TT;  // 256000 rows
  float* gxbuf = (float*)d_ws;                       // M*384 floats
  float* h1buf = gxbuf + (size_t)M * GG;             // M*128 floats

  // 1) gx0 = x @ Wih0^T + bih0   (K=26 exact)
  gemm_bias<26, false><<<dim3(M / 64, 6), dim3(256), 0, stream>>>(
      x, 26, Wih0, bih0, gxbuf, GG, M, GG);

  // 2) layer-0 recurrence -> h1buf
  gru_rec<<<dim3(BB), dim3(512), 0, stream>>>(gxbuf, Whh0, bhh0, h1buf, HH);

  // 3) gx1 = h1 @ Wih1^T + bih1 (reuse gxbuf)
  gemm_bias<128, false><<<dim3(M / 64, 6), dim3(256), 0, stream>>>(
      h1buf, HH, Wih1, bih1, gxbuf, GG, M, GG);

  // 4) layer-1 recurrence -> h2 in d_out rows (stride 136)
  gru_rec<<<dim3(BB), dim3(512), 0, stream>>>(gxbuf, Whh1, bhh1, out, 136);

  // 5) hidden = relu(h2 @ W1^T + b1) -> h1buf
  gemm_bias<128, true><<<dim3(M / 64, 2), dim3(256), 0, stream>>>(
      out, 136, W1, b1, h1buf, HH, M, HH);

  // 6) out = hidden @ W2^T + b2 -> d_out
  gemm_bias<128, false><<<dim3(M / 64, 3), dim3(256), 0, stream>>>(
      h1buf, HH, W2, b2, out, 136, M, 136);
}

// Round 6
// 5746.877 us; speedup vs baseline: 1.5151x; 1.0872x over previous
//
#include <hip/hip_runtime.h>
#include <hip/hip_fp16.h>
#include <cstdint>

#define HH 128
#define GG 384   // 3H
#define TT 4000
#define BB 64

typedef uint32_t u32;

__device__ __forceinline__ float sigmf(float x) {
  return __fdividef(1.0f, 1.0f + __expf(-x));
}
__device__ __forceinline__ float tanh_fast(float x) {
  return __fdividef(2.0f, 1.0f + __expf(-2.0f * x)) - 1.0f;
}

template <int CTRL>
__device__ __forceinline__ float quad_add(float x) {
  int y = __builtin_amdgcn_mov_dpp(__float_as_int(x), CTRL, 0xF, 0xF, true);
  return x + __int_as_float(y);
}

// v_dot2_f32_f16: d = a.x*b.x + a.y*b.y + c  (fp16 mul exact into fp32 acc)
__device__ __forceinline__ float fdot2(u32 a, u32 b, float c) {
  float d;
  asm("v_dot2_f32_f16 %0, %1, %2, %3" : "=v"(d) : "v"(a), "v"(b), "v"(c));
  return d;
}

__device__ __forceinline__ u32 packh2(float a, float b) {
  __half2 h = __floats2half2_rn(a, b);
  union { __half2 h; u32 u; } cv;
  cv.h = h;
  return cv.u;
}

// LDS-only barrier: do NOT drain vmcnt (keeps global prefetch/stores in flight).
__device__ __forceinline__ void wg_barrier_lds() {
  asm volatile("s_waitcnt lgkmcnt(0)" ::: "memory");
  __builtin_amdgcn_s_barrier();
  asm volatile("" ::: "memory");
}

// ---------------------------------------------------------------------------
// FUSED 2-layer GRU recurrence (lag-1 software pipeline).
// One block per batch element, 512 threads = 128 q x 4 k-chunks = 8 waves.
// Period p computes: L0's h1(p) from h1(p-1)+gx0(p), AND L1's h2(p-1) from
// h1(p-1) (Wih1 dot, replaces the gx1 GEMM) + h2(p-2) (Whh1 dot).
// Both layers' latency walls overlap instead of running as two sequential
// 4000-step passes (round-5 lesson: each pass is pinned at ~1320 cy/step
// regardless of instruction count).
// Thread (q,c) holds 9 gate-row chunks as packed half2: Whh0/Wih1/Whh1 rows
// {q,q+128,q+256}, k in [32c,32c+32) -> 144 weight VGPRs. h states fp32 in
// regs (quad-redundant); packed-half2 h in double-buffered LDS.
// ---------------------------------------------------------------------------
__global__ __launch_bounds__(512)
__attribute__((amdgpu_waves_per_eu(2, 2)))
void gru2_fused(
    const float* __restrict__ gx,     // [B,T,384] L0 input proj (incl bih0)
    const float* __restrict__ Whh0,   // [384,128]
    const float* __restrict__ bhh0,   // [384]
    const float* __restrict__ Wih1,   // [384,128]
    const float* __restrict__ bih1,   // [384]
    const float* __restrict__ Whh1,   // [384,128]
    const float* __restrict__ bhh1,   // [384]
    float* __restrict__ hout2,        // [B,T,ldh] L1 hidden states
    int ldh)
{
  __shared__ u32 h1lds[2][80];   // h as half2: 4 chunks x (16 used + 4 pad)
  __shared__ u32 h2lds[2][80];

  const int tid = threadIdx.x;
  const int q = tid >> 2;   // 0..127
  const int c = tid & 3;    // k-chunk
  const int b = blockIdx.x;
  const int rows[3] = { q, q + 128, q + 256 };

  // weights -> packed half2 registers
  u32 w0[3][16], wi[3][16], wh[3][16];
  #pragma unroll
  for (int rr = 0; rr < 3; ++rr) {
    const float4* p0 = reinterpret_cast<const float4*>(Whh0 + (size_t)rows[rr] * HH + c * 32);
    const float4* p1 = reinterpret_cast<const float4*>(Wih1 + (size_t)rows[rr] * HH + c * 32);
    const float4* p2 = reinterpret_cast<const float4*>(Whh1 + (size_t)rows[rr] * HH + c * 32);
    #pragma unroll
    for (int p = 0; p < 8; ++p) {
      float4 v0 = p0[p], v1 = p1[p], v2 = p2[p];
      w0[rr][p * 2 + 0] = packh2(v0.x, v0.y); w0[rr][p * 2 + 1] = packh2(v0.z, v0.w);
      wi[rr][p * 2 + 0] = packh2(v1.x, v1.y); wi[rr][p * 2 + 1] = packh2(v1.z, v1.w);
      wh[rr][p * 2 + 0] = packh2(v2.x, v2.y); wh[rr][p * 2 + 1] = packh2(v2.z, v2.w);
    }
  }
  #pragma unroll
  for (int rr = 0; rr < 3; ++rr)
    #pragma unroll
    for (int kk = 0; kk < 16; ++kk) {
      asm volatile("" : "+v"(w0[rr][kk]));
      asm volatile("" : "+v"(wi[rr][kk]));
      asm volatile("" : "+v"(wh[rr][kk]));
    }

  float bh0[3];
  #pragma unroll
  for (int rr = 0; rr < 3; ++rr) bh0[rr] = bhh0[rows[rr]];
  const float brz0 = bih1[rows[0]] + bhh1[rows[0]];
  const float brz1 = bih1[rows[1]] + bhh1[rows[1]];
  const float bin  = bih1[rows[2]];
  const float bhn  = bhh1[rows[2]];

  for (int i = tid; i < 160; i += 512) {
    (&h1lds[0][0])[i] = 0u;
    (&h2lds[0][0])[i] = 0u;
  }

  const float* gxb = gx + (size_t)b * TT * GG;
  float* houtb = hout2 + (size_t)b * TT * ldh;

  float hprev1 = 0.0f, hprev2 = 0.0f;

  float gxr[4][3];
  #pragma unroll
  for (int p = 0; p < 4; ++p) {
    const float* gxt = gxb + (size_t)p * GG;
    #pragma unroll
    for (int rr = 0; rr < 3; ++rr) gxr[p][rr] = gxt[rows[rr]];
  }

  __syncthreads();

  #pragma unroll 1
  for (int pp = 0; pp <= TT; pp += 4) {
    #pragma unroll
    for (int s = 0; s < 4; ++s) {
      const int p = pp + s;
      const int cur = s & 1, nxt = cur ^ 1;   // pp even => p&1 == s&1
      const bool do0 = (p < TT);              // produce h1(p)
      const bool do1 = (p >= 1) && (p <= TT); // produce h2(p-1)

      // ---- L1 recurrent dots (h2(p-2)) first: h2v dies early ----
      float cr = 0.f, cz = 0.f, chn = 0.f, dr = 0.f, dz = 0.f, dhn = 0.f;
      if (do1) {
        u32 h2v[16];
        const uint4* hp = reinterpret_cast<const uint4*>(&h2lds[cur][c * 20]);
        #pragma unroll
        for (int i = 0; i < 4; ++i) {
          uint4 v = hp[i];
          h2v[i * 4 + 0] = v.x; h2v[i * 4 + 1] = v.y;
          h2v[i * 4 + 2] = v.z; h2v[i * 4 + 3] = v.w;
        }
        #pragma unroll
        for (int k2 = 0; k2 < 16; k2 += 2) {
          cr  = fdot2(h2v[k2],     wh[0][k2],     cr);
          cz  = fdot2(h2v[k2],     wh[1][k2],     cz);
          chn = fdot2(h2v[k2],     wh[2][k2],     chn);
          dr  = fdot2(h2v[k2 + 1], wh[0][k2 + 1], dr);
          dz  = fdot2(h2v[k2 + 1], wh[1][k2 + 1], dz);
          dhn = fdot2(h2v[k2 + 1], wh[2][k2 + 1], dhn);
        }
      }

      // ---- shared read of h1(p-1) ----
      u32 h1v[16];
      {
        const uint4* hp = reinterpret_cast<const uint4*>(&h1lds[cur][c * 20]);
        #pragma unroll
        for (int i = 0; i < 4; ++i) {
          uint4 v = hp[i];
          h1v[i * 4 + 0] = v.x; h1v[i * 4 + 1] = v.y;
          h1v[i * 4 + 2] = v.z; h1v[i * 4 + 3] = v.w;
        }
      }

      // ---- L0 dots (Whh0 . h1(p-1)) ----
      float a0 = 0.f, a1 = 0.f, a2 = 0.f, e0 = 0.f, e1 = 0.f, e2 = 0.f;
      if (do0) {
        #pragma unroll
        for (int k2 = 0; k2 < 16; k2 += 2) {
          a0 = fdot2(h1v[k2],     w0[0][k2],     a0);
          a1 = fdot2(h1v[k2],     w0[1][k2],     a1);
          a2 = fdot2(h1v[k2],     w0[2][k2],     a2);
          e0 = fdot2(h1v[k2 + 1], w0[0][k2 + 1], e0);
          e1 = fdot2(h1v[k2 + 1], w0[1][k2 + 1], e1);
          e2 = fdot2(h1v[k2 + 1], w0[2][k2 + 1], e2);
        }
      }

      // ---- L1 input-projection dots (Wih1 . h1(p-1)) ----
      float cxn = 0.f, dxn = 0.f;
      if (do1) {
        #pragma unroll
        for (int k2 = 0; k2 < 16; k2 += 2) {
          cr  = fdot2(h1v[k2],     wi[0][k2],     cr);
          cz  = fdot2(h1v[k2],     wi[1][k2],     cz);
          cxn = fdot2(h1v[k2],     wi[2][k2],     cxn);
          dr  = fdot2(h1v[k2 + 1], wi[0][k2 + 1], dr);
          dz  = fdot2(h1v[k2 + 1], wi[1][k2 + 1], dz);
          dxn = fdot2(h1v[k2 + 1], wi[2][k2 + 1], dxn);
        }
      }

      // ---- L0 gates ----
      if (do0) {
        a0 += e0; a1 += e1; a2 += e2;
        a0 = quad_add<0xB1>(a0); a0 = quad_add<0x4E>(a0);
        a1 = quad_add<0xB1>(a1); a1 = quad_add<0x4E>(a1);
        a2 = quad_add<0xB1>(a2); a2 = quad_add<0x4E>(a2);
        const float r = sigmf(gxr[s][0] + a0 + bh0[0]);
        const float z = sigmf(gxr[s][1] + a1 + bh0[1]);
        const float n = tanh_fast(gxr[s][2] + r * (a2 + bh0[2]));
        const float h1n = (1.0f - z) * n + z * hprev1;
        hprev1 = h1n;
        if (c == 0) {
          __half* hw = reinterpret_cast<__half*>(&h1lds[nxt][(q >> 5) * 20]);
          hw[q & 31] = __float2half_rn(h1n);
        }
      }

      // ---- L1 gates ----
      if (do1) {
        cr += dr; cz += dz; cxn += dxn; chn += dhn;
        cr  = quad_add<0xB1>(cr);  cr  = quad_add<0x4E>(cr);
        cz  = quad_add<0xB1>(cz);  cz  = quad_add<0x4E>(cz);
        cxn = quad_add<0xB1>(cxn); cxn = quad_add<0x4E>(cxn);
        chn = quad_add<0xB1>(chn); chn = quad_add<0x4E>(chn);
        const float r1 = sigmf(cr + brz0);
        const float z1 = sigmf(cz + brz1);
        const float n1 = tanh_fast(cxn + bin + r1 * (chn + bhn));
        const float h2n = (1.0f - z1) * n1 + z1 * hprev2;
        hprev2 = h2n;
        if (c == 0) {
          __half* hw = reinterpret_cast<__half*>(&h2lds[nxt][(q >> 5) * 20]);
          hw[q & 31] = __float2half_rn(h2n);
          houtb[(size_t)(p - 1) * ldh + q] = h2n;
        }
      }

      // ---- refill gx slot s with gx(p+4) (clamped; harmless at tail) ----
      {
        const int tp = (p + 4 < TT) ? (p + 4) : (TT - 1);
        const float* gxt = gxb + (size_t)tp * GG;
        #pragma unroll
        for (int rr = 0; rr < 3; ++rr) gxr[s][rr] = gxt[rows[rr]];
      }

      wg_barrier_lds();
    }
  }
}

// ---------------------------------------------------------------------------
// Tiled GEMM: C[M,N] = A[M,K] * Bw[N,K]^T + bias (optional ReLU).
// 128x128 tile, K staged in 32-chunks (33KB LDS), 256 threads, 8x8/thread:
// 64 FMA per 16 LDS-b32 reads -> VALU-bound (the 64x64/4x4 version was
// DS-bound: 8 reads per 16 FMA). float4 stores.
// ---------------------------------------------------------------------------
template <int K, bool RELU>
__global__ __launch_bounds__(256) void gemm_bias(
    const float* __restrict__ A, int lda,
    const float* __restrict__ Bw,       // [N, K] row-major
    const float* __restrict__ bias,     // [N]
    float* __restrict__ C, int ldc,
    int M, int N)
{
  __shared__ float As[128][33];
  __shared__ float Bs[128][33];

  const int tid = threadIdx.x;
  const int tx = tid & 15, ty = tid >> 4;
  const int row0 = blockIdx.x * 128, col0 = blockIdx.y * 128;

  float acc[8][8] = {};

  #pragma unroll
  for (int k0 = 0; k0 < K; k0 += 32) {
    const int kc = (K - k0 < 32) ? (K - k0) : 32;   // constant-folds per k0

    #pragma unroll
    for (int l = 0; l < 16; ++l) {
      const int idx = tid + l * 256;
      const int r = idx >> 5, cc = idx & 31;
      As[r][cc] = (cc < kc) ? A[(size_t)(row0 + r) * lda + k0 + cc] : 0.0f;
      const int n = col0 + r;
      Bs[r][cc] = (cc < kc && n < N) ? Bw[(size_t)n * K + k0 + cc] : 0.0f;
    }
    __syncthreads();

    #pragma unroll 4
    for (int kk = 0; kk < kc; ++kk) {
      float av[8], bv[8];
      #pragma unroll
      for (int i = 0; i < 8; ++i) av[i] = As[ty * 8 + i][kk];
      #pragma unroll
      for (int j = 0; j < 8; ++j) bv[j] = Bs[tx * 8 + j][kk];
      #pragma unroll
      for (int i = 0; i < 8; ++i)
        #pragma unroll
        for (int j = 0; j < 8; ++j)
          acc[i][j] = fmaf(av[i], bv[j], acc[i][j]);
    }
    __syncthreads();
  }

  #pragma unroll
  for (int i = 0; i < 8; ++i) {
    const int r = row0 + ty * 8 + i;
    #pragma unroll
    for (int jj = 0; jj < 2; ++jj) {
      const int cn = col0 + tx * 8 + jj * 4;
      if (cn < N) {   // N % 4 == 0 for all our shapes
        float4 v;
        v.x = acc[i][jj * 4 + 0] + bias[cn + 0];
        v.y = acc[i][jj * 4 + 1] + bias[cn + 1];
        v.z = acc[i][jj * 4 + 2] + bias[cn + 2];
        v.w = acc[i][jj * 4 + 3] + bias[cn + 3];
        if (RELU) {
          v.x = v.x > 0.f ? v.x : 0.f; v.y = v.y > 0.f ? v.y : 0.f;
          v.z = v.z > 0.f ? v.z : 0.f; v.w = v.w > 0.f ? v.w : 0.f;
        }
        *reinterpret_cast<float4*>(&C[(size_t)r * ldc + cn]) = v;
      }
    }
  }
}

// ---------------------------------------------------------------------------
extern "C" void kernel_launch(void* const* d_in, const int* in_sizes, int n_in,
                              void* d_out, int out_size, void* d_ws, size_t ws_size,
                              hipStream_t stream) {
  const float* x    = (const float*)d_in[0];
  const float* Wih0 = (const float*)d_in[1];
  const float* Whh0 = (const float*)d_in[2];
  const float* bih0 = (const float*)d_in[3];
  const float* bhh0 = (const float*)d_in[4];
  const float* Wih1 = (const float*)d_in[5];
  const float* Whh1 = (const float*)d_in[6];
  const float* bih1 = (const float*)d_in[7];
  const float* bhh1 = (const float*)d_in[8];
  const float* W1   = (const float*)d_in[9];
  const float* b1   = (const float*)d_in[10];
  const float* W2   = (const float*)d_in[11];
  const float* b2   = (const float*)d_in[12];
  float* out = (float*)d_out;

  const int M = BB * TT;  // 256000 rows
  float* gxbuf = (float*)d_ws;                       // M*384 floats
  float* h1buf = gxbuf + (size_t)M * GG;             // M*128 floats (hidden)

  // 1) gx0 = x @ Wih0^T + bih0   (K=26 exact)
  gemm_bias<26, false><<<dim3(M / 128, 3), dim3(256), 0, stream>>>(
      x, 26, Wih0, bih0, gxbuf, GG, M, GG);

  // 2) fused 2-layer recurrence -> h2 in d_out rows (stride 136).
  //    (gx1 GEMM and h1 global round-trip eliminated.)
  gru2_fused<<<dim3(BB), dim3(512), 0, stream>>>(
      gxbuf, Whh0, bhh0, Wih1, bih1, Whh1, bhh1, out, 136);

  // 3) hidden = relu(h2 @ W1^T + b1) -> h1buf
  gemm_bias<128, true><<<dim3(M / 128, 1), dim3(256), 0, stream>>>(
      out, 136, W1, b1, h1buf, HH, M, HH);

  // 4) out = hidden @ W2^T + b2 -> d_out
  gemm_bias<128, false><<<dim3(M / 128, 2), dim3(256), 0, stream>>>(
      h1buf, HH, W2, b2, out, 136, M, 136);
}